// Round 4
// baseline (553.729 us; speedup 1.0000x reference)
//
#include <hip/hip_runtime.h>
#include <stdint.h>

// Problem: N=131072, D=128, W=16, R=5
//   logit[n,r] = e1[n]^T C_r e2[n],  C_r = sum_w weight[w,r] * M_w
//   out[0] = -mean(log_softmax(logit)[n, rels[n]]),  out[1..N] = expected rating
//
// R4: BN=64 rows/block; wave w = rows [16w,16w+16) x ALL 128 cols.
// All waves share the same B stream (L1 reuse); no LDS atomics (disjoint rows);
// 2 A ds_reads per k4. 3-term bf16 split (hi*hi + hi*lo + lo*hi).

#define NTOT 131072
#define DDIM 128
#define WBAS 16
#define RCLS 5
#define BN   64
#define SA   136     // LDS row stride (bf16); 272 B -> mild 2-way bank aliasing

typedef __attribute__((ext_vector_type(8))) short bf16x8;
typedef __attribute__((ext_vector_type(4))) float f32x4;

__device__ __forceinline__ unsigned short f2bf(float x) {
    union { float f; unsigned u; } v; v.f = x;
    unsigned u = v.u + 0x7FFFu + ((v.u >> 16) & 1u);
    return (unsigned short)(u >> 16);
}
__device__ __forceinline__ float bf2f(unsigned short h) {
    union { float f; unsigned u; } v; v.u = ((unsigned)h) << 16;
    return v.f;
}

// ---- prep: Ct[r][e][d] = bf16 hi/lo of sum_w wsc[w][r]*rel[w][d*128+e]; zero loss ----
__global__ __launch_bounds__(256) void prep_kernel(
    const float* __restrict__ rel_embeds,    // [W, D*D]  ([d][e] inner)
    const float* __restrict__ wsc,           // [W, R]
    unsigned short* __restrict__ Cth,        // [R, 128, 128]  ([e][d] inner)
    unsigned short* __restrict__ Ctl,
    float* __restrict__ out)
{
    int idx = blockIdx.x * 256 + threadIdx.x;     // 0 .. 81919
    if (idx == 0) out[0] = 0.0f;
    if (idx < RCLS * DDIM * DDIM) {
        int r   = idx >> 14;
        int rem = idx & 16383;
        int e   = rem >> 7;
        int d   = rem & 127;
        float acc = 0.0f;
#pragma unroll
        for (int w = 0; w < WBAS; ++w)
            acc += wsc[w * RCLS + r] * rel_embeds[w * 16384 + d * 128 + e];
        unsigned short hi = f2bf(acc);
        Cth[idx] = hi;
        Ctl[idx] = f2bf(acc - bf2f(hi));
    }
}

// ---- main fused kernel ----
__global__ __launch_bounds__(256, 3) void bilinear_mfma_kernel(
    const float* __restrict__ e1g,           // [N, D]
    const float* __restrict__ e2g,           // [N, D]
    const unsigned short* __restrict__ Cth,  // [R, 128, 128] bf16 hi
    const unsigned short* __restrict__ Ctl,  // bf16 lo
    const int*   __restrict__ rels,
    float* __restrict__ out,                 // [1 + N]
    float inv_n)
{
    __shared__ __align__(16) unsigned short s_hi[BN][SA];
    __shared__ __align__(16) unsigned short s_lo[BN][SA];
    __shared__ float s_logit[BN][RCLS];      // written exactly once per slot

    const int tid  = threadIdx.x;
    const int n0   = blockIdx.x * BN;
    const int lane = tid & 63;
    const int w    = tid >> 6;      // wave id -> row band [16w, 16w+16)
    const int l15  = lane & 15;
    const int q    = lane >> 4;

    // e2 in C-fragment layout for this wave's rows:
    //   e2r[nt][i] = e2[n0 + 16w + 4q + i][16nt + l15]
    float e2r[8][4];
#pragma unroll
    for (int i = 0; i < 4; ++i) {
        const float* p = e2g + (size_t)(n0 + 16 * w + 4 * q + i) * DDIM + l15;
#pragma unroll
        for (int nt = 0; nt < 8; ++nt) e2r[nt][i] = p[16 * nt];
    }

    // stage e1 -> bf16 hi/lo in LDS (64 rows x 32 float4, all 256 threads)
#pragma unroll
    for (int it = 0; it < 8; ++it) {
        int idx = it * 256 + tid;
        int row = idx >> 5, c4 = idx & 31;
        float4 v = ((const float4*)(e1g + (size_t)(n0 + row) * DDIM))[c4];
        unsigned short hx = f2bf(v.x), hy = f2bf(v.y), hz = f2bf(v.z), hw = f2bf(v.w);
        *(ushort4*)&s_hi[row][c4 * 4] = make_ushort4(hx, hy, hz, hw);
        *(ushort4*)&s_lo[row][c4 * 4] = make_ushort4(
            f2bf(v.x - bf2f(hx)), f2bf(v.y - bf2f(hy)),
            f2bf(v.z - bf2f(hz)), f2bf(v.w - bf2f(hw)));
    }
    __syncthreads();

    // per-lane B offsets (bf16 elems): Ct[r][e = 16nt + l15][k = q*8 + ...]
    int bofs[8];
#pragma unroll
    for (int nt = 0; nt < 8; ++nt)
        bofs[nt] = (16 * nt + l15) * DDIM + q * 8;

    const unsigned short* bh = Cth;
    const unsigned short* bl = Ctl;

    for (int r = 0; r < RCLS; ++r) {
        f32x4 acc[8];
#pragma unroll
        for (int nt = 0; nt < 8; ++nt) {
            f32x4 z = {0.0f, 0.0f, 0.0f, 0.0f};
            acc[nt] = z;
        }

#pragma unroll
        for (int k4 = 0; k4 < 4; ++k4) {
            bf16x8 bhv[8], blv[8];
#pragma unroll
            for (int nt = 0; nt < 8; ++nt)
                bhv[nt] = *(const bf16x8*)(bh + bofs[nt] + k4 * 32);
#pragma unroll
            for (int nt = 0; nt < 8; ++nt)
                blv[nt] = *(const bf16x8*)(bl + bofs[nt] + k4 * 32);
            bf16x8 ah = *(const bf16x8*)&s_hi[16 * w + l15][k4 * 32 + q * 8];
            bf16x8 al = *(const bf16x8*)&s_lo[16 * w + l15][k4 * 32 + q * 8];
#pragma unroll
            for (int nt = 0; nt < 8; ++nt) {
                acc[nt] = __builtin_amdgcn_mfma_f32_16x16x32_bf16(ah, bhv[nt], acc[nt], 0, 0, 0);
                acc[nt] = __builtin_amdgcn_mfma_f32_16x16x32_bf16(ah, blv[nt], acc[nt], 0, 0, 0);
                acc[nt] = __builtin_amdgcn_mfma_f32_16x16x32_bf16(al, bhv[nt], acc[nt], 0, 0, 0);
            }
        }

        // contract with e2; reduce over the 16 l15-lanes; plain LDS write (disjoint rows)
#pragma unroll
        for (int i = 0; i < 4; ++i) {
            float p = 0.0f;
#pragma unroll
            for (int nt = 0; nt < 8; ++nt) p += acc[nt][i] * e2r[nt][i];
            p += __shfl_xor(p, 1);
            p += __shfl_xor(p, 2);
            p += __shfl_xor(p, 4);
            p += __shfl_xor(p, 8);
            if (l15 == 0) s_logit[16 * w + 4 * q + i][r] = p;
        }

        bh += 16384;
        bl += 16384;
    }
    __syncthreads();

    // epilogue: one thread per row
    if (tid < BN) {
        float l[RCLS];
#pragma unroll
        for (int r = 0; r < RCLS; ++r) l[r] = s_logit[tid][r];
        float mx = l[0];
#pragma unroll
        for (int r = 1; r < RCLS; ++r) mx = fmaxf(mx, l[r]);
        float e[RCLS], se = 0.0f;
#pragma unroll
        for (int r = 0; r < RCLS; ++r) { e[r] = __expf(l[r] - mx); se += e[r]; }
        float inv_se = 1.0f / se;
        float pred = 0.0f;
#pragma unroll
        for (int r = 0; r < RCLS; ++r) pred += (float)(r + 1) * e[r] * inv_se;
        out[1 + n0 + tid] = pred;

        int rel = rels[n0 + tid];
        float lossc = -(l[rel] - mx - logf(se)) * inv_n;
#pragma unroll
        for (int m = 1; m <= 32; m <<= 1) lossc += __shfl_xor(lossc, m);
        if (lane == 0) atomicAdd(out, lossc);
    }
}

extern "C" void kernel_launch(void* const* d_in, const int* in_sizes, int n_in,
                              void* d_out, int out_size, void* d_ws, size_t ws_size,
                              hipStream_t stream) {
    const float* e1   = (const float*)d_in[0];
    const float* e2   = (const float*)d_in[1];
    const float* rele = (const float*)d_in[2];
    const float* wsc  = (const float*)d_in[3];
    const int*   rels = (const int*)d_in[4];
    float* out = (float*)d_out;

    unsigned short* Cth = (unsigned short*)d_ws;             // 163840 B
    unsigned short* Ctl = Cth + RCLS * DDIM * DDIM;          // +163840 B

    prep_kernel<<<320, 256, 0, stream>>>(rele, wsc, Cth, Ctl, out);
    bilinear_mfma_kernel<<<NTOT / BN, 256, 0, stream>>>(
        e1, e2, Cth, Ctl, rels, out, 1.0f / (float)NTOT);
}

// Round 5
// 240.725 us; speedup vs baseline: 2.3003x; 2.3003x over previous
//
#include <hip/hip_runtime.h>
#include <stdint.h>

// Problem: N=131072, D=128, W=16, R=5
//   logit[n,r] = e1[n]^T C_r e2[n],  C_r = sum_w weight[w,r] * M_w
//   out[0] = -mean(log_softmax(logit)[n, rels[n]]),  out[1..N] = expected rating
//
// R5: R3 partition (wave w = 64 rows x cols [32w,32w+32)) + explicit
// distance-1 B prefetch over a flat 20-stage (r,k4) stream. B double-buffer
// is only 32 VGPRs, so no spill (R4's 16-fragment buffer spilled).
// 3-term bf16 split (hi*hi + hi*lo + lo*hi). No LDS atomics (per-wave partials).

#define NTOT 131072
#define DDIM 128
#define WBAS 16
#define RCLS 5
#define BN   64
#define SA   136     // LDS row stride (bf16); 272 B -> 2-way bank aliasing (free)

typedef __attribute__((ext_vector_type(8))) short bf16x8;
typedef __attribute__((ext_vector_type(4))) float f32x4;

__device__ __forceinline__ unsigned short f2bf(float x) {
    union { float f; unsigned u; } v; v.f = x;
    unsigned u = v.u + 0x7FFFu + ((v.u >> 16) & 1u);
    return (unsigned short)(u >> 16);
}
__device__ __forceinline__ float bf2f(unsigned short h) {
    union { float f; unsigned u; } v; v.u = ((unsigned)h) << 16;
    return v.f;
}

// ---- prep: one thread per (e,d); computes all 5 r; coalesced writes ----
__global__ __launch_bounds__(256) void prep_kernel(
    const float* __restrict__ rel_embeds,    // [W, D*D]  ([d][e] inner)
    const float* __restrict__ wsc,           // [W, R]
    unsigned short* __restrict__ Cth,        // [R, 128, 128]  ([e][d] inner)
    unsigned short* __restrict__ Ctl,
    float* __restrict__ out)
{
    int ed = blockIdx.x * 256 + threadIdx.x;   // 0 .. 16383 ; e = ed>>7, d = ed&127
    if (ed == 0) out[0] = 0.0f;
    int e = ed >> 7, d = ed & 127;
    float acc[RCLS];
#pragma unroll
    for (int r = 0; r < RCLS; ++r) acc[r] = 0.0f;
#pragma unroll
    for (int w = 0; w < WBAS; ++w) {
        float v = rel_embeds[w * 16384 + d * 128 + e];
#pragma unroll
        for (int r = 0; r < RCLS; ++r) acc[r] += wsc[w * RCLS + r] * v;
    }
#pragma unroll
    for (int r = 0; r < RCLS; ++r) {
        unsigned short hi = f2bf(acc[r]);
        Cth[r * 16384 + ed] = hi;                       // [r][e][d], d fastest: coalesced
        Ctl[r * 16384 + ed] = f2bf(acc[r] - bf2f(hi));
    }
}

// ---- main fused kernel ----
__global__ __launch_bounds__(256, 3) void bilinear_mfma_kernel(
    const float* __restrict__ e1g,           // [N, D]
    const float* __restrict__ e2g,           // [N, D]
    const unsigned short* __restrict__ Cth,  // [R, 128, 128] bf16 hi
    const unsigned short* __restrict__ Ctl,  // bf16 lo
    const int*   __restrict__ rels,
    float* __restrict__ out,                 // [1 + N]
    float inv_n)
{
    __shared__ __align__(16) unsigned short s_hi[BN][SA];
    __shared__ __align__(16) unsigned short s_lo[BN][SA];
    __shared__ float s_part[BN][4][RCLS];    // per-wave partial logits (no atomics)

    const int tid  = threadIdx.x;
    const int n0   = blockIdx.x * BN;
    const int lane = tid & 63;
    const int w    = tid >> 6;      // wave id -> col band [32w, 32w+32)
    const int l15  = lane & 15;
    const int q    = lane >> 4;

    // e2 in C-fragment layout: e2r[mt][nt][i] = e2[n0+16mt+4q+i][32w+16nt+l15]
    float e2r[4][2][4];
#pragma unroll
    for (int mt = 0; mt < 4; ++mt)
#pragma unroll
        for (int i = 0; i < 4; ++i) {
            const float* p = e2g + (size_t)(n0 + 16 * mt + 4 * q + i) * DDIM + 32 * w + l15;
            e2r[mt][0][i] = p[0];
            e2r[mt][1][i] = p[16];
        }

    // stage e1 -> bf16 hi/lo in LDS (64 rows x 32 float4)
#pragma unroll
    for (int it = 0; it < 8; ++it) {
        int idx = it * 256 + tid;
        int row = idx >> 5, c4 = idx & 31;
        float4 v = ((const float4*)(e1g + (size_t)(n0 + row) * DDIM))[c4];
        unsigned short hx = f2bf(v.x), hy = f2bf(v.y), hz = f2bf(v.z), hw = f2bf(v.w);
        *(ushort4*)&s_hi[row][c4 * 4] = make_ushort4(hx, hy, hz, hw);
        *(ushort4*)&s_lo[row][c4 * 4] = make_ushort4(
            f2bf(v.x - bf2f(hx)), f2bf(v.y - bf2f(hy)),
            f2bf(v.z - bf2f(hz)), f2bf(v.w - bf2f(hw)));
    }
    __syncthreads();

    const int bofs0 = (32 * w + l15) * DDIM + q * 8;   // cols [32w, 32w+16)
    const int bofs1 = bofs0 + 16 * DDIM;               // cols [32w+16, 32w+32)

    // ---- flat 20-stage (r,k4) stream with distance-1 B prefetch ----
    bf16x8 nb0 = *(const bf16x8*)(Cth + bofs0);
    bf16x8 nb1 = *(const bf16x8*)(Cth + bofs1);
    bf16x8 nl0 = *(const bf16x8*)(Ctl + bofs0);
    bf16x8 nl1 = *(const bf16x8*)(Ctl + bofs1);

#pragma unroll
    for (int r = 0; r < RCLS; ++r) {
        f32x4 acc[4][2];
#pragma unroll
        for (int mt = 0; mt < 4; ++mt)
#pragma unroll
            for (int nt = 0; nt < 2; ++nt) {
                f32x4 z = {0.0f, 0.0f, 0.0f, 0.0f};
                acc[mt][nt] = z;
            }

#pragma unroll
        for (int k4 = 0; k4 < 4; ++k4) {
            // rotate: current <- prefetched
            bf16x8 cb0 = nb0, cb1 = nb1, cl0 = nl0, cl1 = nl1;

            // issue next stage's B loads (stage s+1 of 20; clamp to 0 at end)
            int s1 = r * 4 + k4 + 1;
            int nofs = (s1 < 20) ? ((s1 >> 2) * 16384 + (s1 & 3) * 32) : 0;
            nb0 = *(const bf16x8*)(Cth + nofs + bofs0);
            nb1 = *(const bf16x8*)(Cth + nofs + bofs1);
            nl0 = *(const bf16x8*)(Ctl + nofs + bofs0);
            nl1 = *(const bf16x8*)(Ctl + nofs + bofs1);

            // A fragments from LDS (just-in-time)
            bf16x8 ah[4], al[4];
#pragma unroll
            for (int mt = 0; mt < 4; ++mt) {
                ah[mt] = *(const bf16x8*)&s_hi[16 * mt + l15][k4 * 32 + q * 8];
                al[mt] = *(const bf16x8*)&s_lo[16 * mt + l15][k4 * 32 + q * 8];
            }

            // 24 MFMAs on current B
#pragma unroll
            for (int mt = 0; mt < 4; ++mt) {
                acc[mt][0] = __builtin_amdgcn_mfma_f32_16x16x32_bf16(ah[mt], cb0, acc[mt][0], 0, 0, 0);
                acc[mt][0] = __builtin_amdgcn_mfma_f32_16x16x32_bf16(ah[mt], cl0, acc[mt][0], 0, 0, 0);
                acc[mt][0] = __builtin_amdgcn_mfma_f32_16x16x32_bf16(al[mt], cb0, acc[mt][0], 0, 0, 0);
                acc[mt][1] = __builtin_amdgcn_mfma_f32_16x16x32_bf16(ah[mt], cb1, acc[mt][1], 0, 0, 0);
                acc[mt][1] = __builtin_amdgcn_mfma_f32_16x16x32_bf16(ah[mt], cl1, acc[mt][1], 0, 0, 0);
                acc[mt][1] = __builtin_amdgcn_mfma_f32_16x16x32_bf16(al[mt], cb1, acc[mt][1], 0, 0, 0);
            }
        }

        // contract with e2; reduce over the 16 l15-lanes; disjoint LDS write
#pragma unroll
        for (int mt = 0; mt < 4; ++mt)
#pragma unroll
            for (int i = 0; i < 4; ++i) {
                float p = acc[mt][0][i] * e2r[mt][0][i] + acc[mt][1][i] * e2r[mt][1][i];
                p += __shfl_xor(p, 1);
                p += __shfl_xor(p, 2);
                p += __shfl_xor(p, 4);
                p += __shfl_xor(p, 8);
                if (l15 == 0) s_part[16 * mt + 4 * q + i][w][r] = p;
            }
    }
    __syncthreads();

    // epilogue: one thread per row; sum the 4 per-wave partials
    if (tid < BN) {
        float l[RCLS];
#pragma unroll
        for (int r = 0; r < RCLS; ++r)
            l[r] = s_part[tid][0][r] + s_part[tid][1][r]
                 + s_part[tid][2][r] + s_part[tid][3][r];
        float mx = l[0];
#pragma unroll
        for (int r = 1; r < RCLS; ++r) mx = fmaxf(mx, l[r]);
        float e[RCLS], se = 0.0f;
#pragma unroll
        for (int r = 0; r < RCLS; ++r) { e[r] = __expf(l[r] - mx); se += e[r]; }
        float inv_se = 1.0f / se;
        float pred = 0.0f;
#pragma unroll
        for (int r = 0; r < RCLS; ++r) pred += (float)(r + 1) * e[r] * inv_se;
        out[1 + n0 + tid] = pred;

        int rel = rels[n0 + tid];
        float lossc = -(l[rel] - mx - logf(se)) * inv_n;
#pragma unroll
        for (int m = 1; m <= 32; m <<= 1) lossc += __shfl_xor(lossc, m);
        if (lane == 0) atomicAdd(out, lossc);
    }
}

extern "C" void kernel_launch(void* const* d_in, const int* in_sizes, int n_in,
                              void* d_out, int out_size, void* d_ws, size_t ws_size,
                              hipStream_t stream) {
    const float* e1   = (const float*)d_in[0];
    const float* e2   = (const float*)d_in[1];
    const float* rele = (const float*)d_in[2];
    const float* wsc  = (const float*)d_in[3];
    const int*   rels = (const int*)d_in[4];
    float* out = (float*)d_out;

    unsigned short* Cth = (unsigned short*)d_ws;             // 163840 B
    unsigned short* Ctl = Cth + RCLS * DDIM * DDIM;          // +163840 B

    prep_kernel<<<64, 256, 0, stream>>>(rele, wsc, Cth, Ctl, out);
    bilinear_mfma_kernel<<<NTOT / BN, 256, 0, stream>>>(
        e1, e2, Cth, Ctl, rels, out, 1.0f / (float)NTOT);
}